// Round 7
// baseline (268.374 us; speedup 1.0000x reference)
//
#include <hip/hip_runtime.h>
#include <hip/hip_fp16.h>

// Problem constants: B=16, N=128, H=128, BD=64, P=256
using f16x4 = __attribute__((ext_vector_type(4))) _Float16;
using f32x4 = __attribute__((ext_vector_type(4))) float;

__device__ __forceinline__ f16x4 ld_f16x4(const void* p) {
    return *reinterpret_cast<const f16x4*>(p);
}

// ---------------------------------------------------------------------------
// Prep kernel A: W2bt[p][k] = W2[128+k][p] (f16 transposed, 64 f16/row), and
// W3 -> W3s: f16, chunked [kc][p'][32k] (16KB per kc-chunk, 64B per p'-row).
// Within-row byte order matches the reader: lane (l15,lk) reads k =
// s2*16 + lk*4 + e at byte (2*s2+(lk>>1))*16 + (lk&1)*8 + e*2.
// ---------------------------------------------------------------------------
__global__ void sp_wconv(const float* __restrict__ W2, const float* __restrict__ W3,
                         _Float16* __restrict__ W2bt, _Float16* __restrict__ W3s) {
    int t = blockIdx.x * 256 + threadIdx.x;   // grid covers 65536
    if (t < 16384) {
        int p = t >> 6, k = t & 63;
        W2bt[t] = (_Float16)W2[(128 + k) * 256 + p];
    }
    {
        int kc = t >> 13, rem = t & 8191;
        int prow = rem >> 5, inrow = rem & 31;   // f16 index within 64B row
        int gidx = inrow >> 3, within = inrow & 7;
        int lklo = within >> 2, e = within & 3;
        int s2 = gidx >> 1, lkhi = gidx & 1;
        int k = kc * 32 + s2 * 16 + (lkhi * 2 + lklo) * 4 + e;
        W3s[t] = (_Float16)W3[k * 256 + prow];
    }
}

// ---------------------------------------------------------------------------
// Prep kernel B: hp16[b*128+j][p] = hid[b,j,:] @ W2[0:128,p] + b2[p]  (f16)
// ---------------------------------------------------------------------------
__global__ void sp_hpart(const float* __restrict__ hs, const float* __restrict__ W2,
                         const float* __restrict__ b2, _Float16* __restrict__ hp16) {
    __shared__ float sh[8 * 128];
    int rb = blockIdx.x * 8;
    int tid = threadIdx.x;
    for (int t = tid; t < 1024; t += 256) sh[t] = hs[rb * 128 + t];
    __syncthreads();
    float acc[8];
    float bb = b2[tid];
#pragma unroll
    for (int r = 0; r < 8; ++r) acc[r] = bb;
    for (int k = 0; k < 128; ++k) {
        float w = W2[k * 256 + tid];
#pragma unroll
        for (int r = 0; r < 8; ++r) acc[r] += sh[r * 128 + k] * w;
    }
#pragma unroll
    for (int r = 0; r < 8; ++r) hp16[(rb + r) * 256 + tid] = (_Float16)acc[r];
}

// ---------------------------------------------------------------------------
// Main kernel: one block per (b,i). 4 waves, wave w owns j in [32w,32w+32).
// mfma_f32_16x16x16f16 (A[m=l%16][k=4*(l/16)+e], B[k][n=l%16],
// D[m=4*(l/16)+r][n=l%16]).
//
// NO LDS STAGING: W2bt (32KB), W3s (128KB), hp16 (64KB/block) are all
// L1/L2-resident and read as per-lane MFMA fragments DIRECTLY from global
// (Common-mistake #7: don't stage what cache-fits). LDS = 4KB pool only.
//   GEMM1 (transposed) per-pt: acc = W2bt(A,M=p) x enc(B,N=j);
//     u[jt][pt] = relu(acc + hp16[j]) in registers = GEMM2 A-frags (k=pt).
//   GEMM2, two p'-passes (eacc[2][8]): emb = U @ W3s, K=256, kc fully
//     unrolled, B-frags f16x4 straight from global (coalesced 512B/instr).
//   pooled[p'] = max_{j != i} emb[j,p'] + b3[p'] -> d_out row bi.
// ---------------------------------------------------------------------------
__global__ __launch_bounds__(256, 3) void sp_main(
    const float* __restrict__ pos, const float* __restrict__ W1,
    const float* __restrict__ b1, const float* __restrict__ b3,
    const _Float16* __restrict__ hp16, const _Float16* __restrict__ W2bt,
    const _Float16* __restrict__ W3s, float* __restrict__ pool) {
    __shared__ float sPool[1024];

    const int bi = blockIdx.x;
    const int b = bi >> 7, i = bi & 127;
    const int tid = threadIdx.x;
    const int wave = tid >> 6, lane = tid & 63;
    const int l15 = lane & 15, lk = lane >> 4;

    const float pix = pos[(b * 128 + i) * 2 + 0];
    const float piy = pos[(b * 128 + i) * 2 + 1];

    // --- W1/b1 vectorized (each lane's fixed 16 k-slots) -------------------
    f32x4 w1x[4], w1y[4], bb1[4];
#pragma unroll
    for (int s = 0; s < 4; ++s) {
        int k0 = s * 16 + lk * 4;
        w1x[s] = *reinterpret_cast<const f32x4*>(W1 + k0);
        w1y[s] = *reinterpret_cast<const f32x4*>(W1 + 64 + k0);
        bb1[s] = *reinterpret_cast<const f32x4*>(b1 + k0);
    }

    // --- enc as B-fragments: B[k=s*16+4lk+e][n=j], j = wave*32+jt*16+l15 ---
    f16x4 benc[2][4];
#pragma unroll
    for (int jt = 0; jt < 2; ++jt) {
        int j = wave * 32 + jt * 16 + l15;
        float rx = pos[(b * 128 + j) * 2 + 0] - pix;
        float ry = pos[(b * 128 + j) * 2 + 1] - piy;
#pragma unroll
        for (int s = 0; s < 4; ++s) {
            f16x4 v;
#pragma unroll
            for (int e = 0; e < 4; ++e) {
                float t = fmaf(rx, w1x[s][e], fmaf(ry, w1y[s][e], bb1[s][e]));
                v[e] = (_Float16)(t > 0.f ? t : 0.f);
            }
            benc[jt][s] = v;
        }
    }

    // --- GEMM1 (transposed) per-pt + in-register U build -------------------
    // lane holds D[p = pt*16+4lk+r][j = wave*32+jt*16+l15]
    const _Float16* hp0 = hp16 + (b * 128 + wave * 32 + l15) * 256 + lk * 4;
    const _Float16* hp1 = hp0 + 16 * 256;
    f16x4 u[2][16];
#pragma unroll
    for (int pt = 0; pt < 16; ++pt) {
        f32x4 a0 = (f32x4){0.f, 0.f, 0.f, 0.f};
        f32x4 a1 = (f32x4){0.f, 0.f, 0.f, 0.f};
#pragma unroll
        for (int s = 0; s < 4; ++s) {
            f16x4 aw = ld_f16x4(W2bt + (pt * 16 + l15) * 64 + s * 16 + lk * 4);
            a0 = __builtin_amdgcn_mfma_f32_16x16x16f16(aw, benc[0][s], a0, 0, 0, 0);
            a1 = __builtin_amdgcn_mfma_f32_16x16x16f16(aw, benc[1][s], a1, 0, 0, 0);
        }
        f16x4 h0 = ld_f16x4(hp0 + pt * 16);
        f16x4 h1 = ld_f16x4(hp1 + pt * 16);
        f16x4 v0, v1;
#pragma unroll
        for (int r = 0; r < 4; ++r) {
            float t0 = a0[r] + (float)h0[r];
            float t1 = a1[r] + (float)h1[r];
            v0[r] = (_Float16)(t0 > 0.f ? t0 : 0.f);
            v1[r] = (_Float16)(t1 > 0.f ? t1 : 0.f);
        }
        u[0][pt] = v0;
        u[1][pt] = v1;
    }

    // --- GEMM2: emb = U @ W3s, B-frags direct from global ------------------
#pragma unroll
    for (int pass = 0; pass < 2; ++pass) {
        f32x4 eacc[2][8];
#pragma unroll
        for (int jt = 0; jt < 2; ++jt)
#pragma unroll
            for (int pt = 0; pt < 8; ++pt) eacc[jt][pt] = (f32x4){0.f, 0.f, 0.f, 0.f};

        // per-lane base: row p' = pass*128 + pt*16 + l15 (64B rows),
        // byte-in-row = s2*32 + (lk>>1)*16 + (lk&1)*8, chunk stride 16KB
        const char* base = (const char*)W3s + (pass * 128 + l15) * 64 +
                           (lk >> 1) * 16 + (lk & 1) * 8;
#pragma unroll
        for (int kc = 0; kc < 8; ++kc) {
#pragma unroll
            for (int s2 = 0; s2 < 2; ++s2) {
                const int ks = kc * 2 + s2;
#pragma unroll
                for (int pt = 0; pt < 8; ++pt) {
                    f16x4 bf = ld_f16x4(base + kc * 16384 + s2 * 32 + pt * 1024);
                    eacc[0][pt] = __builtin_amdgcn_mfma_f32_16x16x16f16(u[0][ks], bf, eacc[0][pt], 0, 0, 0);
                    eacc[1][pt] = __builtin_amdgcn_mfma_f32_16x16x16f16(u[1][ks], bf, eacc[1][pt], 0, 0, 0);
                }
            }
        }

        // --- masked max over this wave's 32 j, reduce across lane groups ---
#pragma unroll
        for (int pt = 0; pt < 8; ++pt) {
            float m = -INFINITY;
#pragma unroll
            for (int jt = 0; jt < 2; ++jt) {
#pragma unroll
                for (int r = 0; r < 4; ++r) {
                    int row = wave * 32 + jt * 16 + lk * 4 + r;
                    float v = eacc[jt][pt][r];
                    if (row != i) m = fmaxf(m, v);
                }
            }
            m = fmaxf(m, __shfl_xor(m, 16));
            m = fmaxf(m, __shfl_xor(m, 32));
            if (lane < 16) sPool[wave * 256 + (pass * 8 + pt) * 16 + lane] = m;
        }
    }
    __syncthreads();
    {
        float v = fmaxf(fmaxf(sPool[tid], sPool[256 + tid]),
                        fmaxf(sPool[512 + tid], sPool[768 + tid]));
        pool[bi * 256 + tid] = v + b3[tid];    // d_out row bi (write-only)
    }
}

// ---------------------------------------------------------------------------
// Final: io = io @ Wout + bout, IN PLACE on d_out (8 rows per block; rows
// staged to LDS behind a barrier before any write -> in-place safe).
// ---------------------------------------------------------------------------
__global__ void sp_out(const float* __restrict__ Wout, const float* __restrict__ bout,
                       float* __restrict__ io) {
    __shared__ float sp[8 * 256];
    int rb = blockIdx.x * 8;
    int tid = threadIdx.x;
    for (int t = tid; t < 2048; t += 256) sp[t] = io[rb * 256 + t];
    __syncthreads();
    float acc[8];
    float bb = bout[tid];
#pragma unroll
    for (int r = 0; r < 8; ++r) acc[r] = bb;
    for (int k = 0; k < 256; ++k) {
        float w = Wout[k * 256 + tid];
#pragma unroll
        for (int r = 0; r < 8; ++r) acc[r] += sp[r * 256 + k] * w;
    }
#pragma unroll
    for (int r = 0; r < 8; ++r) io[(rb + r) * 256 + tid] = acc[r];
}

extern "C" void kernel_launch(void* const* d_in, const int* in_sizes, int n_in,
                              void* d_out, int out_size, void* d_ws, size_t ws_size,
                              hipStream_t stream) {
    const float* hs   = (const float*)d_in[0];
    const float* pos  = (const float*)d_in[1];
    const float* W1   = (const float*)d_in[2];
    const float* b1   = (const float*)d_in[3];
    const float* W2   = (const float*)d_in[4];
    const float* b2   = (const float*)d_in[5];
    const float* W3   = (const float*)d_in[6];
    const float* b3   = (const float*)d_in[7];
    const float* Wout = (const float*)d_in[8];
    const float* bout = (const float*)d_in[9];
    float* out = (float*)d_out;

    // ws layout: hp16 1MB | W2bt 32KB | W3s 128KB  (~1.2MB total)
    _Float16* hp16 = (_Float16*)d_ws;
    _Float16* W2bt = (_Float16*)((char*)d_ws + (1 << 20));
    _Float16* W3s  = (_Float16*)((char*)d_ws + (1 << 20) + 32768);

    sp_wconv<<<256, 256, 0, stream>>>(W2, W3, W2bt, W3s);
    sp_hpart<<<256, 256, 0, stream>>>(hs, W2, b2, hp16);
    sp_main<<<2048, 256, 0, stream>>>(pos, W1, b1, b3, hp16, W2bt, W3s, out);
    sp_out<<<256, 256, 0, stream>>>(Wout, bout, out);
}

// Round 8
// 160.823 us; speedup vs baseline: 1.6688x; 1.6688x over previous
//
#include <hip/hip_runtime.h>
#include <hip/hip_fp16.h>

// Problem constants: B=16, N=128, H=128, BD=64, P=256
using f16x4 = __attribute__((ext_vector_type(4))) _Float16;
using f16x8 = __attribute__((ext_vector_type(8))) _Float16;
using f32x4 = __attribute__((ext_vector_type(4))) float;

__device__ __forceinline__ f16x4 ld_f16x4(const void* p) {
    return *reinterpret_cast<const f16x4*>(p);
}
__device__ __forceinline__ f16x8 ld_f16x8(const void* p) {
    return *reinterpret_cast<const f16x8*>(p);
}

// ---------------------------------------------------------------------------
// Prep kernel A:
//  W2bt[p][k] = W2[128+k][p]  (f16 plain transpose, 64 f16/row) for GEMM1.
//  W3 -> W3s for GEMM2 (K=32 MFMA): chunk ks (8 chunks of 32 k), row p'
//  (256 rows x 64B), inner f16 index q = lk*8+e holds W3[32ks + sigma(lk,e)][p']
//  with sigma(lk,e) = (e>>2)*16 + 4*lk + (e&3).  sigma matches the u-packing
//  (GEMM1 C/D quads) -- k-permutation consistent across A and B, so the
//  contraction is exact.
// ---------------------------------------------------------------------------
__global__ void sp_wconv(const float* __restrict__ W2, const float* __restrict__ W3,
                         _Float16* __restrict__ W2bt, _Float16* __restrict__ W3s) {
    int t = blockIdx.x * 256 + threadIdx.x;   // grid covers 65536
    if (t < 16384) {
        int p = t >> 6, k = t & 63;
        W2bt[t] = (_Float16)W2[(128 + k) * 256 + p];
    }
    {
        int ks = t >> 13, rem = t & 8191;
        int prow = rem >> 5, inner = rem & 31;   // inner = lk*8 + e
        int lk = inner >> 3, e = inner & 7;
        int k = ks * 32 + ((e & 4) << 2) + (lk << 2) + (e & 3);
        W3s[t] = (_Float16)W3[k * 256 + prow];
    }
}

// ---------------------------------------------------------------------------
// Prep kernel B: hp16[b*128+j][p] = hid[b,j,:] @ W2[0:128,p] + b2[p]  (f16)
// ---------------------------------------------------------------------------
__global__ void sp_hpart(const float* __restrict__ hs, const float* __restrict__ W2,
                         const float* __restrict__ b2, _Float16* __restrict__ hp16) {
    __shared__ float sh[8 * 128];
    int rb = blockIdx.x * 8;
    int tid = threadIdx.x;
    for (int t = tid; t < 1024; t += 256) sh[t] = hs[rb * 128 + t];
    __syncthreads();
    float acc[8];
    float bb = b2[tid];
#pragma unroll
    for (int r = 0; r < 8; ++r) acc[r] = bb;
    for (int k = 0; k < 128; ++k) {
        float w = W2[k * 256 + tid];
#pragma unroll
        for (int r = 0; r < 8; ++r) acc[r] += sh[r * 128 + k] * w;
    }
#pragma unroll
    for (int r = 0; r < 8; ++r) hp16[(rb + r) * 256 + tid] = (_Float16)acc[r];
}

// ---------------------------------------------------------------------------
// Main kernel: one block per (b,i). 4 waves, wave w owns j in [32w,32w+32).
//
// GEMM1 (K=16, mfma_f32_16x16x16f16, transposed): acc = W2bt(A,M=p) x
//   enc(B,N=j); lane holds D[p=pt*16+4lk+r][j=wave*32+jt*16+l15].
//   u[jt][ks] (f16x8) = relu(acc+hp) packed from pt=2ks (e<4) and pt=2ks+1
//   (e>=4)  ==  K=32 A-frag under sigma. Entirely in registers.
// GEMM2 (K=32, mfma_f32_16x16x32_f16): emb = U @ W3, 8 ks-chunks; W3 chunk
//   (16KB) staged to LDS rows padded to 80B (2-way banks = free),
//   double-buffered, reg-staged issue-early/write-late, 1 barrier/chunk.
//   B-frags: one ds_read_b128 per (pt,ks).
// pooled[p'] = max_{j != i} emb[j,p'] + b3[p'] -> d_out row bi (write-only).
// LDS: 2 x 20KB W3 + 4KB pool = 44KB. Regs ~225 (u64+eacc128+staging) -> (256,2).
// ---------------------------------------------------------------------------
__global__ __launch_bounds__(256, 2) void sp_main(
    const float* __restrict__ pos, const float* __restrict__ W1,
    const float* __restrict__ b1, const float* __restrict__ b3,
    const _Float16* __restrict__ hp16, const _Float16* __restrict__ W2bt,
    const _Float16* __restrict__ W3s, float* __restrict__ pool) {
    __shared__ __align__(16) char sW3[2][20480];   // 256 rows x 80B
    __shared__ float sPool[1024];

    const int bi = blockIdx.x;
    const int b = bi >> 7, i = bi & 127;
    const int tid = threadIdx.x;
    const int wave = tid >> 6, lane = tid & 63;
    const int l15 = lane & 15, lk = lane >> 4;

    const float pix = pos[(b * 128 + i) * 2 + 0];
    const float piy = pos[(b * 128 + i) * 2 + 1];

    // --- W1/b1 vectorized (each lane's fixed 16 k-slots) -------------------
    f32x4 w1x[4], w1y[4], bb1[4];
#pragma unroll
    for (int s = 0; s < 4; ++s) {
        int k0 = s * 16 + lk * 4;
        w1x[s] = *reinterpret_cast<const f32x4*>(W1 + k0);
        w1y[s] = *reinterpret_cast<const f32x4*>(W1 + 64 + k0);
        bb1[s] = *reinterpret_cast<const f32x4*>(b1 + k0);
    }

    // --- enc as B-fragments (K=16): B[k=s*16+4lk+e][n=j] -------------------
    f16x4 benc[2][4];
#pragma unroll
    for (int jt = 0; jt < 2; ++jt) {
        int j = wave * 32 + jt * 16 + l15;
        float rx = pos[(b * 128 + j) * 2 + 0] - pix;
        float ry = pos[(b * 128 + j) * 2 + 1] - piy;
#pragma unroll
        for (int s = 0; s < 4; ++s) {
            f16x4 v;
#pragma unroll
            for (int e = 0; e < 4; ++e) {
                float t = fmaf(rx, w1x[s][e], fmaf(ry, w1y[s][e], bb1[s][e]));
                v[e] = (_Float16)(t > 0.f ? t : 0.f);
            }
            benc[jt][s] = v;
        }
    }

    // --- GEMM1 (transposed, K=16) + pack u = K=32 A-frags ------------------
    const _Float16* hp0 = hp16 + (b * 128 + wave * 32 + l15) * 256 + lk * 4;
    const _Float16* hp1 = hp0 + 16 * 256;
    f16x8 u[2][8];
#pragma unroll
    for (int pt = 0; pt < 16; ++pt) {
        f32x4 a0 = (f32x4){0.f, 0.f, 0.f, 0.f};
        f32x4 a1 = (f32x4){0.f, 0.f, 0.f, 0.f};
#pragma unroll
        for (int s = 0; s < 4; ++s) {
            f16x4 aw = ld_f16x4(W2bt + (pt * 16 + l15) * 64 + s * 16 + lk * 4);
            a0 = __builtin_amdgcn_mfma_f32_16x16x16f16(aw, benc[0][s], a0, 0, 0, 0);
            a1 = __builtin_amdgcn_mfma_f32_16x16x16f16(aw, benc[1][s], a1, 0, 0, 0);
        }
        f16x4 h0 = ld_f16x4(hp0 + pt * 16);
        f16x4 h1 = ld_f16x4(hp1 + pt * 16);
        const int ks = pt >> 1, half = (pt & 1) * 4;
#pragma unroll
        for (int r = 0; r < 4; ++r) {
            float t0 = a0[r] + (float)h0[r];
            float t1 = a1[r] + (float)h1[r];
            u[0][ks][half + r] = (_Float16)(t0 > 0.f ? t0 : 0.f);
            u[1][ks][half + r] = (_Float16)(t1 > 0.f ? t1 : 0.f);
        }
    }

    // --- GEMM2: emb = U @ W3 (K=32), LDS dbuf, 1 barrier/chunk -------------
    f32x4 eacc[2][16];
#pragma unroll
    for (int jt = 0; jt < 2; ++jt)
#pragma unroll
        for (int pt = 0; pt < 16; ++pt) eacc[jt][pt] = (f32x4){0.f, 0.f, 0.f, 0.f};

    const uint4* W3v = (const uint4*)W3s;   // 1024 uint4 per 16KB chunk
    {   // prologue: stage chunk 0 into buf 0 (80B-padded scatter)
#pragma unroll
        for (int it = 0; it < 4; ++it) {
            int q = tid + it * 256;
            uint4 g = W3v[q];
            *(uint4*)(sW3[0] + (q >> 2) * 80 + (q & 3) * 16) = g;
        }
    }
    __syncthreads();

#pragma unroll
    for (int ks = 0; ks < 8; ++ks) {
        const int buf = ks & 1;
        uint4 g[4];
        if (ks < 7) {   // issue next-chunk loads early (hide under MFMA)
            const uint4* src = W3v + (ks + 1) * 1024;
#pragma unroll
            for (int it = 0; it < 4; ++it) g[it] = src[tid + it * 256];
        }
#pragma unroll
        for (int pt = 0; pt < 16; ++pt) {
            f16x8 bf = ld_f16x8(sW3[buf] + (pt * 16 + l15) * 80 + lk * 16);
            eacc[0][pt] = __builtin_amdgcn_mfma_f32_16x16x32_f16(u[0][ks], bf, eacc[0][pt], 0, 0, 0);
            eacc[1][pt] = __builtin_amdgcn_mfma_f32_16x16x32_f16(u[1][ks], bf, eacc[1][pt], 0, 0, 0);
        }
        if (ks < 7) {   // write-late into the other buffer
#pragma unroll
            for (int it = 0; it < 4; ++it) {
                int q = tid + it * 256;
                *(uint4*)(sW3[buf ^ 1] + (q >> 2) * 80 + (q & 3) * 16) = g[it];
            }
        }
        __syncthreads();
    }

    // --- masked max over j, cross-lane + cross-wave reduce ----------------
    // eacc: row j = wave*32 + jt*16 + 4lk + r, col p' = pt*16 + l15
    float pm[16];
#pragma unroll
    for (int pt = 0; pt < 16; ++pt) {
        float m = -INFINITY;
#pragma unroll
        for (int jt = 0; jt < 2; ++jt) {
#pragma unroll
            for (int r = 0; r < 4; ++r) {
                int row = wave * 32 + jt * 16 + lk * 4 + r;
                float v = eacc[jt][pt][r];
                if (row != i) m = fmaxf(m, v);
            }
        }
        m = fmaxf(m, __shfl_xor(m, 16));
        m = fmaxf(m, __shfl_xor(m, 32));
        pm[pt] = m;
    }
    if (lane < 16) {
#pragma unroll
        for (int pt = 0; pt < 16; ++pt) sPool[wave * 256 + pt * 16 + lane] = pm[pt];
    }
    __syncthreads();
    {
        float v = fmaxf(fmaxf(sPool[tid], sPool[256 + tid]),
                        fmaxf(sPool[512 + tid], sPool[768 + tid]));
        pool[bi * 256 + tid] = v + b3[tid];    // d_out row bi (write-only)
    }
}

// ---------------------------------------------------------------------------
// Final: io = io @ Wout + bout, IN PLACE on d_out (8 rows per block; rows
// staged to LDS behind a barrier before any write -> in-place safe).
// ---------------------------------------------------------------------------
__global__ void sp_out(const float* __restrict__ Wout, const float* __restrict__ bout,
                       float* __restrict__ io) {
    __shared__ float sp[8 * 256];
    int rb = blockIdx.x * 8;
    int tid = threadIdx.x;
    for (int t = tid; t < 2048; t += 256) sp[t] = io[rb * 256 + t];
    __syncthreads();
    float acc[8];
    float bb = bout[tid];
#pragma unroll
    for (int r = 0; r < 8; ++r) acc[r] = bb;
    for (int k = 0; k < 256; ++k) {
        float w = Wout[k * 256 + tid];
#pragma unroll
        for (int r = 0; r < 8; ++r) acc[r] += sp[r * 256 + k] * w;
    }
#pragma unroll
    for (int r = 0; r < 8; ++r) io[(rb + r) * 256 + tid] = acc[r];
}

extern "C" void kernel_launch(void* const* d_in, const int* in_sizes, int n_in,
                              void* d_out, int out_size, void* d_ws, size_t ws_size,
                              hipStream_t stream) {
    const float* hs   = (const float*)d_in[0];
    const float* pos  = (const float*)d_in[1];
    const float* W1   = (const float*)d_in[2];
    const float* b1   = (const float*)d_in[3];
    const float* W2   = (const float*)d_in[4];
    const float* b2   = (const float*)d_in[5];
    const float* W3   = (const float*)d_in[6];
    const float* b3   = (const float*)d_in[7];
    const float* Wout = (const float*)d_in[8];
    const float* bout = (const float*)d_in[9];
    float* out = (float*)d_out;

    // ws layout: hp16 1MB | W2bt 32KB | W3s 128KB  (~1.2MB total)
    _Float16* hp16 = (_Float16*)d_ws;
    _Float16* W2bt = (_Float16*)((char*)d_ws + (1 << 20));
    _Float16* W3s  = (_Float16*)((char*)d_ws + (1 << 20) + 32768);

    sp_wconv<<<256, 256, 0, stream>>>(W2, W3, W2bt, W3s);
    sp_hpart<<<256, 256, 0, stream>>>(hs, W2, b2, hp16);
    sp_main<<<2048, 256, 0, stream>>>(pos, W1, b1, b3, hp16, W2bt, W3s, out);
    sp_out<<<256, 256, 0, stream>>>(Wout, bout, out);
}